// Round 2
// baseline (64.521 us; speedup 1.0000x reference)
//
#include <hip/hip_runtime.h>
#include <math.h>

#define S_LEN 512
#define D_DIM 64

typedef __attribute__((ext_vector_type(8))) short bf16x8;
typedef __attribute__((ext_vector_type(4))) float f32x4;
typedef __attribute__((ext_vector_type(4))) unsigned int u32x4;
typedef unsigned int u32;
typedef unsigned long long u64;

__device__ __forceinline__ float pow2i(int e) {  // 2^e, e in normal range
    return __int_as_float((e + 127) << 23);
}
// (bf16(hi) << 16) | bf16(lo) — both values exactly representable in bf16
__device__ __forceinline__ u32 pack_bf2(float lo, float hi) {
    return __builtin_amdgcn_perm(__float_as_uint(hi), __float_as_uint(lo), 0x07060302u);
}

extern "C" __global__ void __launch_bounds__(512, 2)
mxattn(const float* __restrict__ gmq, const int* __restrict__ geq,
       const float* __restrict__ gmk, const int* __restrict__ gek,
       const float* __restrict__ gmv, const int* __restrict__ gev,
       float* __restrict__ gout)
{
    // K' = mk*2^(ek-7) (exact bf16), [t][d], XOR-swizzled rows
    __shared__ __attribute__((aligned(16))) short Ksw[S_LEN * D_DIM];   // 64 KB
    // V' = mv*2^(ev-7) (exact bf16), [d][t] transposed, XOR-swizzled rows
    __shared__ __attribute__((aligned(16))) short Vsw[D_DIM * S_LEN];   // 64 KB
    // per-wave double-buffered P exchange slots: [wave][parity][lane][16B]
    __shared__ __attribute__((aligned(16))) char Pex[8 * 2 * 64 * 16];  // 16 KB

    const int b    = blockIdx.x;
    const int tid  = threadIdx.x;
    const int lane = tid & 63;
    const int wave = tid >> 6;
    const int l15  = lane & 15;
    const int lg   = lane >> 4;

    const float* mqb = gmq + (size_t)b * (S_LEN * D_DIM);
    const float* mkb = gmk + (size_t)b * (S_LEN * D_DIM);
    const float* mvb = gmv + (size_t)b * (S_LEN * D_DIM);
    const int* eqb = geq + b * S_LEN;
    const int* ekb = gek + b * S_LEN;
    const int* evb = gev + b * S_LEN;

    char* kbase = (char*)Ksw;
    char* vbase = (char*)Vsw;

    // ---------------- staging (float4-vectorized) ----------------
    #pragma unroll
    for (int it = 0; it < 16; ++it) {
        int idx = it * 512 + tid;
        int t = idx >> 4, d0 = (idx & 15) * 4;
        float ks = pow2i(ekb[t] - 7);
        f32x4 mk4 = *(const f32x4*)(mkb + t * 64 + d0);
        u32 klo = pack_bf2(mk4[0] * ks, mk4[1] * ks);
        u32 khi = pack_bf2(mk4[2] * ks, mk4[3] * ks);
        *(u64*)(kbase + t * 128 + ((2 * d0) ^ ((t & 7) << 4))) = ((u64)khi << 32) | klo;
        float vs = pow2i(evb[t] - 7);
        f32x4 mv4 = *(const f32x4*)(mvb + t * 64 + d0);
        #pragma unroll
        for (int i = 0; i < 4; ++i) {
            int d = d0 + i;
            *(short*)(vbase + d * 1024 + ((2 * t) ^ ((d & 7) << 4))) =
                (short)(__float_as_uint(mv4[i] * vs) >> 16);
        }
    }
    // per-pass row scales 2^(eq-7) for this lane's s-row
    float sqp[4];
    #pragma unroll
    for (int p = 0; p < 4; ++p) sqp[p] = pow2i(eqb[p * 128 + wave * 16 + l15] - 7);
    __syncthreads();

    const float L2E = 1.44269504088896340736f;
    const int p_ = lg >> 1;                    // tile parity this lane consumes
    const int srcA = l15 + ((lg & 1) << 5);    // exchange source lanes
    const int srcAoff = srcA * 16 + (p_ << 3);

    for (int pass = 0; pass < 4; ++pass) {
        const int r0 = pass * 128 + wave * 16;

        // ---- Q B-frags (col = s = l15, k = d = lg*8+j), raw integer mantissas ----
        bf16x8 qa0, qa1;
        {
            const float* qp = mqb + (size_t)(r0 + l15) * 64 + lg * 8;
            f32x4 a0 = *(const f32x4*)(qp);
            f32x4 a1 = *(const f32x4*)(qp + 4);
            f32x4 a2 = *(const f32x4*)(qp + 32);
            f32x4 a3 = *(const f32x4*)(qp + 36);
            u32x4 q0 = { pack_bf2(a0[0], a0[1]), pack_bf2(a0[2], a0[3]),
                         pack_bf2(a1[0], a1[1]), pack_bf2(a1[2], a1[3]) };
            u32x4 q1 = { pack_bf2(a2[0], a2[1]), pack_bf2(a2[2], a2[3]),
                         pack_bf2(a3[0], a3[1]), pack_bf2(a3[2], a3[3]) };
            qa0 = *(bf16x8*)&q0;
            qa1 = *(bf16x8*)&q1;
        }

        // ---- QK^T swapped: acc[tt][j] = S[t = tt*16+lg*4+j][s = r0+l15] ----
        // acc = 2^(ek[t]-7) * (integer dot) — exact in fp32
        f32x4 acc[32];
        #pragma unroll
        for (int tt = 0; tt < 32; ++tt) acc[tt] = f32x4{0.f, 0.f, 0.f, 0.f};
        #pragma unroll
        for (int tt = 0; tt < 32; ++tt) {
            int t = tt * 16 + l15;
            int row = t * 128, sw = (t & 7) << 4;
            bf16x8 kf0 = *(const bf16x8*)(kbase + row + ((16 * lg) ^ sw));
            bf16x8 kf1 = *(const bf16x8*)(kbase + row + ((64 + 16 * lg) ^ sw));
            acc[tt] = __builtin_amdgcn_mfma_f32_16x16x32_bf16(kf0, qa0, acc[tt], 0, 0, 0);
            acc[tt] = __builtin_amdgcn_mfma_f32_16x16x32_bf16(kf1, qa1, acc[tt], 0, 0, 0);
        }

        // ---- row amax (scores >= 0: inputs are nonneg ints) ----
        float am0 = 0.f, am1 = 0.f, am2 = 0.f, am3 = 0.f;
        #pragma unroll
        for (int tt = 0; tt < 32; ++tt) {
            am0 = fmaxf(am0, acc[tt][0]); am1 = fmaxf(am1, acc[tt][1]);
            am2 = fmaxf(am2, acc[tt][2]); am3 = fmaxf(am3, acc[tt][3]);
        }
        float amax = fmaxf(fmaxf(am0, am1), fmaxf(am2, am3));
        amax = fmaxf(amax, __shfl_xor(amax, 16));
        amax = fmaxf(amax, __shfl_xor(amax, 32));

        // ---- score quant scale: e_s = clip(floor(log2(amax*sq)), -8, 7) ----
        const float sq = sqp[pass];
        float as = fmaxf(amax * sq, 1.17549435e-38f);
        int es = (int)((__float_as_uint(as) >> 23) & 0xFFu) - 127;
        es = es < -8 ? -8 : (es > 7 ? 7 : es);
        const float c1 = sq * pow2i(7 - es);       // m = rint(acc*c1), exact product
        const float M = fminf(rintf(amax * c1), 127.f);   // row max of m (monotone)
        const float nML2E = -M * L2E;

        // ---- fused quant + exp (native v_exp) + row sum ----
        float s0 = 0.f, s1 = 0.f, s2 = 0.f, s3 = 0.f;
        #pragma unroll
        for (int tt = 0; tt < 32; ++tt) {
            f32x4 a = acc[tt];
            float m0 = fminf(rintf(a[0] * c1), 127.f);
            float m1 = fminf(rintf(a[1] * c1), 127.f);
            float m2 = fminf(rintf(a[2] * c1), 127.f);
            float m3 = fminf(rintf(a[3] * c1), 127.f);
            a[0] = exp2f(fmaf(m0, L2E, nML2E));
            a[1] = exp2f(fmaf(m1, L2E, nML2E));
            a[2] = exp2f(fmaf(m2, L2E, nML2E));
            a[3] = exp2f(fmaf(m3, L2E, nML2E));
            s0 += a[0]; s1 += a[1]; s2 += a[2]; s3 += a[3];
            acc[tt] = a;
        }
        float sum = (s0 + s1) + (s2 + s3);
        sum += __shfl_xor(sum, 16);
        sum += __shfl_xor(sum, 32);

        // ---- prob quant: max prob = 1/sum; fused scale ----
        float pm = fmaxf(1.0f / sum, 1.17549435e-38f);
        int ep = (int)((__float_as_uint(pm) >> 23) & 0xFFu) - 127;
        ep = ep < -8 ? -8 : (ep > 7 ? 7 : ep);
        const float sp = pow2i(7 - ep) / sum;      // m_p = rint(e * sp)
        const float osc = pow2i(ep - 7);           // ctx row scale

        // ---- PV: per-chunk slot exchange (1 b128 write + 2 b64 reads) ----
        f32x4 ctx[4];
        #pragma unroll
        for (int dt = 0; dt < 4; ++dt) ctx[dt] = f32x4{0.f, 0.f, 0.f, 0.f};
        #pragma unroll
        for (int c = 0; c < 16; ++c) {
            char* pb = Pex + (size_t)(wave * 2 + (c & 1)) * 1024;
            f32x4 aA = acc[2 * c], aB = acc[2 * c + 1];
            float m0 = fminf(rintf(aA[0] * sp), 127.f);
            float m1 = fminf(rintf(aA[1] * sp), 127.f);
            float m2 = fminf(rintf(aA[2] * sp), 127.f);
            float m3 = fminf(rintf(aA[3] * sp), 127.f);
            float m4 = fminf(rintf(aB[0] * sp), 127.f);
            float m5 = fminf(rintf(aB[1] * sp), 127.f);
            float m6 = fminf(rintf(aB[2] * sp), 127.f);
            float m7 = fminf(rintf(aB[3] * sp), 127.f);
            u32x4 wv = { pack_bf2(m0, m1), pack_bf2(m2, m3),
                         pack_bf2(m4, m5), pack_bf2(m6, m7) };
            *(u32x4*)(pb + lane * 16) = wv;                     // ds_write_b128
            asm volatile("s_waitcnt lgkmcnt(0)" ::: "memory");  // wave-private: writes -> reads
            u64 pa = *(const u64*)(pb + srcAoff);               // srcA pair
            u64 pc = *(const u64*)(pb + srcAoff + 256);         // srcB pair (+16 lanes)
            union { u64 q[2]; bf16x8 h; } pu;
            pu.q[0] = pa; pu.q[1] = pc;
            bf16x8 pf = pu.h;   // A-frag: P[s=l15][t = c*32 + lg*8 + jj]
            int tbase = 2 * (c * 32 + 8 * lg);
            #pragma unroll
            for (int dt = 0; dt < 4; ++dt) {
                int d = dt * 16 + l15;
                bf16x8 vf = *(const bf16x8*)(vbase + d * 1024 + (tbase ^ ((d & 7) << 4)));
                ctx[dt] = __builtin_amdgcn_mfma_f32_16x16x32_bf16(pf, vf, ctx[dt], 0, 0, 0);
            }
        }

        // ---- epilogue: ctx rows follow C-layout (row = lg*4+j) ----
        float oscr[4];
        #pragma unroll
        for (int j = 0; j < 4; ++j) oscr[j] = __shfl(osc, lg * 4 + j);
        float cv[4][4];
        float a4[4] = {0.f, 0.f, 0.f, 0.f};
        #pragma unroll
        for (int dt = 0; dt < 4; ++dt)
            #pragma unroll
            for (int j = 0; j < 4; ++j) {
                float x = ctx[dt][j] * oscr[j];
                cv[dt][j] = x;
                a4[j] = fmaxf(a4[j], fabsf(x));
            }
        #pragma unroll
        for (int j = 0; j < 4; ++j) {
            #pragma unroll
            for (int off = 1; off < 16; off <<= 1)
                a4[j] = fmaxf(a4[j], __shfl_xor(a4[j], off));
        }
        float csc[4], oo[4];
        #pragma unroll
        for (int j = 0; j < 4; ++j) {
            float a = fmaxf(a4[j], 1.17549435e-38f);
            int ec = (int)((__float_as_uint(a) >> 23) & 0xFFu) - 127;
            ec = ec < -8 ? -8 : (ec > 7 ? 7 : ec);
            csc[j] = pow2i(7 - ec);
            oo[j] = pow2i(ec - 7);
        }
        #pragma unroll
        for (int dt = 0; dt < 4; ++dt)
            #pragma unroll
            for (int j = 0; j < 4; ++j) {
                float m = rintf(cv[dt][j] * csc[j]);
                m = fminf(fmaxf(m, -128.f), 127.f);
                gout[((size_t)b * S_LEN + r0 + lg * 4 + j) * D_DIM + dt * 16 + l15] = m * oo[j];
            }
    }
}

extern "C" void kernel_launch(void* const* d_in, const int* in_sizes, int n_in,
                              void* d_out, int out_size, void* d_ws, size_t ws_size,
                              hipStream_t stream) {
    const float* mq = (const float*)d_in[0];
    const int*   eq = (const int*)d_in[1];
    const float* mk = (const float*)d_in[2];
    const int*   ek = (const int*)d_in[3];
    const float* mv = (const float*)d_in[4];
    const int*   ev = (const int*)d_in[5];
    float* out = (float*)d_out;
    int B = in_sizes[1] / S_LEN;   // 256
    mxattn<<<B, 512, 0, stream>>>(mq, eq, mk, ek, mv, ev, out);
}